// Round 2
// baseline (76.802 us; speedup 1.0000x reference)
//
#include <hip/hip_runtime.h>

// CenterLoss: loss = sum(clip(distmat * onehot_mask, 1e-12, 1e12)) / B
// Only distmat[b, labels[b]] survives the mask; the (B*C - B) exact zeros
// each clamp to 1e-12 -> closed-form constant. So: per-row squared distance
// x[b] vs centers[labels[b]], clamp per row, sum, + constant, / B.
//
// Fused single-kernel version: 256 blocks x 256 threads, 16 rows/block
// (4 rows/wave -> 16 independent float4 loads/lane for ILP), block LDS
// reduce, one atomicAdd per block onto out[0] (zeroed by a 4-byte memset
// node). Saves one kernel dispatch node vs the two-kernel version.

#define BATCH 4096
#define DIM 512
#define NUM_CLASSES 10000
#define ROWS_PER_WAVE 4
#define WAVES_PER_BLOCK 4
#define ROWS_PER_BLOCK (ROWS_PER_WAVE * WAVES_PER_BLOCK)   // 16
#define NUM_BLOCKS (BATCH / ROWS_PER_BLOCK)                // 256

__global__ __launch_bounds__(256) void center_loss_fused(
    const float* __restrict__ x,
    const int* __restrict__ labels,
    const float* __restrict__ centers,
    float* __restrict__ out)
{
    const int wave = threadIdx.x >> 6;   // 0..3
    const int lane = threadIdx.x & 63;   // 0..63
    const int row0 = blockIdx.x * ROWS_PER_BLOCK + wave * ROWS_PER_WAVE;

    // Issue all 16 16B loads up front — 16 outstanding VMEM ops per lane.
    float4 a[ROWS_PER_WAVE][2], b[ROWS_PER_WAVE][2];
    #pragma unroll
    for (int r = 0; r < ROWS_PER_WAVE; ++r) {
        const int row = row0 + r;
        const int lbl = labels[row];                       // wave-uniform -> scalar
        const float4* xp = (const float4*)(x + (size_t)row * DIM);
        const float4* cp = (const float4*)(centers + (size_t)lbl * DIM);
        a[r][0] = xp[lane];
        a[r][1] = xp[lane + 64];
        b[r][0] = cp[lane];
        b[r][1] = cp[lane + 64];
    }

    float acc[ROWS_PER_WAVE];
    #pragma unroll
    for (int r = 0; r < ROWS_PER_WAVE; ++r) {
        float d, s = 0.0f;
        d = a[r][0].x - b[r][0].x; s += d * d;
        d = a[r][0].y - b[r][0].y; s += d * d;
        d = a[r][0].z - b[r][0].z; s += d * d;
        d = a[r][0].w - b[r][0].w; s += d * d;
        d = a[r][1].x - b[r][1].x; s += d * d;
        d = a[r][1].y - b[r][1].y; s += d * d;
        d = a[r][1].z - b[r][1].z; s += d * d;
        d = a[r][1].w - b[r][1].w; s += d * d;
        acc[r] = s;
    }

    // wave-64 shuffle reduction, 4 rows through the same tree
    #pragma unroll
    for (int off = 32; off > 0; off >>= 1) {
        #pragma unroll
        for (int r = 0; r < ROWS_PER_WAVE; ++r)
            acc[r] += __shfl_down(acc[r], off, 64);
    }

    __shared__ float s_wave[WAVES_PER_BLOCK];
    if (lane == 0) {
        // clamp is per matrix entry, i.e. per row distance
        float w = 0.0f;
        #pragma unroll
        for (int r = 0; r < ROWS_PER_WAVE; ++r)
            w += fminf(fmaxf(acc[r], 1e-12f), 1e12f);
        s_wave[wave] = w;
    }
    __syncthreads();
    if (threadIdx.x == 0) {
        float blk = s_wave[0] + s_wave[1] + s_wave[2] + s_wave[3];
        float v = blk * (1.0f / BATCH);
        if (blockIdx.x == 0) {
            // (B*C - B) zero entries clamped to 1e-12, pre-divided by B
            v += (float)(NUM_CLASSES - 1) * 1e-12f;
        }
        atomicAdd(out, v);
    }
}

extern "C" void kernel_launch(void* const* d_in, const int* in_sizes, int n_in,
                              void* d_out, int out_size, void* d_ws, size_t ws_size,
                              hipStream_t stream) {
    const float* x       = (const float*)d_in[0];   // (4096, 512) f32
    const int*   labels  = (const int*)d_in[1];     // (4096,) int
    const float* centers = (const float*)d_in[2];   // (10000, 512) f32
    float* out = (float*)d_out;                     // scalar loss

    hipMemsetAsync(out, 0, sizeof(float), stream);  // tiny memset node
    center_loss_fused<<<NUM_BLOCKS, 256, 0, stream>>>(x, labels, centers, out);
}